// Round 3
// baseline (3183.762 us; speedup 1.0000x reference)
//
#include <hip/hip_runtime.h>
#include <stdint.h>

typedef unsigned short u16;
typedef unsigned int u32;
typedef __attribute__((ext_vector_type(4))) float f32x4;
typedef __attribute__((ext_vector_type(8))) short bf16x8;

#define NB 128      // graphs
#define LL 256      // nodes per graph
#define DD 128      // hidden
#define EDGES 524288
#define EPG 4096    // edges per graph
#define NN (NB*LL)

__device__ __forceinline__ float bf2f(u16 u) {
    union { u32 i; float f; } v; v.i = ((u32)u) << 16; return v.f;
}
__device__ __forceinline__ u16 f2bf(float f) {
    union { float f; u32 i; } v; v.f = f;
    u32 i = v.i;
    u32 r = (i + 0x7fffu + ((i >> 16) & 1u)) >> 16;   // RNE
    return (u16)r;
}
__device__ __forceinline__ float matfn(float a, float dv) {
    if (a != 0.f) return (a == 1.2f) ? 1.1f : a;
    return (dv == 0.f) ? 0.f : exp2f((1.f - dv) * 0.5849625007211562f); // 1.5^(1-dis)
}
__device__ __forceinline__ void dmax(float* slot, float d) {
    atomicMax((unsigned int*)slot, __float_as_uint(d));   // valid for non-negative floats
}

// ---------------- prep kernels ----------------

__global__ __launch_bounds__(256) void build_matrix_k(const float* __restrict__ adj,
                                                      const float* __restrict__ dis,
                                                      float* __restrict__ mat, int n) {
    int i = blockIdx.x * 256 + threadIdx.x;
    if (i >= n) return;
    mat[i] = matfn(adj[i], dis[i]);
}

__global__ __launch_bounds__(256) void build_wconvT0_k(const float* __restrict__ rel,
                                                       const float* __restrict__ root,
                                                       u16* __restrict__ dst) {
    int i = blockIdx.x * 256 + threadIdx.x;   // 128*128
    int m = i >> 7, k = i & 127;
    float v = 0.f;
    if (k < 40) v = rel[k * 128 + m];
    else if (k >= 64 && k < 104) v = root[(k - 64) * 128 + m];
    dst[m * 128 + k] = f2bf(v);
}

__global__ __launch_bounds__(256) void build_wconvT_k(const float* __restrict__ rel,
                                                      const float* __restrict__ root,
                                                      u16* __restrict__ dst) {
    int i = blockIdx.x * 256 + threadIdx.x;   // 128*256
    int m = i >> 8, k = i & 255;
    float v = (k < 128) ? rel[k * 128 + m] : root[(k - 128) * 128 + m];
    dst[m * 256 + k] = f2bf(v);
}

__global__ __launch_bounds__(256) void build_wqkvT_k(const float* __restrict__ wq,
                                                     const float* __restrict__ wk,
                                                     const float* __restrict__ wv,
                                                     u16* __restrict__ dst) {
    int i = blockIdx.x * 256 + threadIdx.x;   // 768*128
    int m = i >> 7, k = i & 127;
    const float* s = (m < 256) ? wq : (m < 512) ? wk : wv;
    int mm = m & 255;
    dst[m * 128 + k] = f2bf(s[k * 256 + mm]);
}

__global__ __launch_bounds__(256) void transpose_cast_k(const float* __restrict__ src,
                                                        u16* __restrict__ dst, int K, int M) {
    int i = blockIdx.x * 256 + threadIdx.x;
    if (i >= K * M) return;
    int m = i / K, k = i - m * K;
    dst[i] = f2bf(src[k * M + m]);   // dst [M][K]
}

__global__ __launch_bounds__(256) void zero_f32(float* __restrict__ p, int n) {
    int i = blockIdx.x * 256 + threadIdx.x;
    if (i < n) p[i] = 0.f;
}

// ---------------- graph aggregation ----------------

__global__ __launch_bounds__(256) void agg_kernel(const u16* __restrict__ h,
                                                  const int* __restrict__ srcI,
                                                  const int* __restrict__ dstI,
                                                  const float* __restrict__ ew,
                                                  u16* __restrict__ Acat) {
    __shared__ __align__(16) float acc[LL * DD];   // 128 KB
    int b = blockIdx.x, t = threadIdx.x;
    for (int i = t; i < LL * DD; i += 256) acc[i] = 0.f;
    __syncthreads();
    int e0 = b * EPG, nbase = b * LL;
    int d4 = (t & 31) * 4, esub = t >> 5;
    for (int e = e0 + esub; e < e0 + EPG; e += 8) {
        int s = srcI[e];
        int dd = dstI[e] - nbase;
        float w = ew[e];
        ushort4 xv = *(const ushort4*)(h + (size_t)s * DD + d4);
        atomicAdd(&acc[dd * DD + d4 + 0], w * bf2f(xv.x));
        atomicAdd(&acc[dd * DD + d4 + 1], w * bf2f(xv.y));
        atomicAdd(&acc[dd * DD + d4 + 2], w * bf2f(xv.z));
        atomicAdd(&acc[dd * DD + d4 + 3], w * bf2f(xv.w));
    }
    __syncthreads();
    for (int i = t; i < LL * DD; i += 256) {
        int node = i >> 7, dd = i & 127;
        size_t ro = (size_t)(nbase + node) * 256;
        Acat[ro + dd] = f2bf(acc[i]);
        Acat[ro + 128 + dd] = h[(size_t)(nbase + node) * DD + dd];
    }
}

__global__ __launch_bounds__(256) void agg0_kernel(const float* __restrict__ x,
                                                   const int* __restrict__ srcI,
                                                   const int* __restrict__ dstI,
                                                   const float* __restrict__ ew,
                                                   u16* __restrict__ Acat) {
    __shared__ __align__(16) float acc[LL * 40];
    int b = blockIdx.x, t = threadIdx.x;
    for (int i = t; i < LL * 40; i += 256) acc[i] = 0.f;
    __syncthreads();
    int e0 = b * EPG, nbase = b * LL;
    int chunk = t & 15, esub = t >> 4;
    for (int e = e0 + esub; e < e0 + EPG; e += 16) {
        int s = srcI[e];
        int dd = dstI[e] - nbase;
        float w = ew[e];
        if (chunk < 10) {
            float4 xv = *(const float4*)(x + (size_t)s * 40 + chunk * 4);
            atomicAdd(&acc[dd * 40 + chunk * 4 + 0], w * xv.x);
            atomicAdd(&acc[dd * 40 + chunk * 4 + 1], w * xv.y);
            atomicAdd(&acc[dd * 40 + chunk * 4 + 2], w * xv.z);
            atomicAdd(&acc[dd * 40 + chunk * 4 + 3], w * xv.w);
        }
    }
    __syncthreads();
    for (int i = t; i < LL * 128; i += 256) {
        int node = i >> 7, c = i & 127;
        float v = 0.f;
        if (c < 40) v = acc[node * 40 + c];
        else if (c >= 64 && c < 104) v = x[(size_t)(nbase + node) * 40 + (c - 64)];
        Acat[(size_t)(nbase + node) * 128 + c] = f2bf(v);
    }
}

// ---------------- bf16 GEMM (m97 structure) ----------------
// OUTMODE: 0 = f32 store, 1 = bf16 store, 2 = f32 store + f32 bias (final output)

template<int OUTMODE>
__global__ __launch_bounds__(256) void gemm_bt(const u16* __restrict__ A,
                                               const u16* __restrict__ BT,
                                               void* __restrict__ Out,
                                               const float* __restrict__ bias,
                                               int K, int Mtot) {
    __shared__ __align__(16) u16 lds[8192];   // A 8KB | B 8KB  ([128][32] bf16 each, linear)
    char* ldsc = (char*)lds;
    int t = threadIdx.x, lane = t & 63, wid = t >> 6;
    int row0 = blockIdx.x * 128, col0 = blockIdx.y * 128;

    f32x4 zero = {0.f, 0.f, 0.f, 0.f};
    f32x4 acc[4][4];
#pragma unroll
    for (int mt = 0; mt < 4; ++mt)
#pragma unroll
        for (int nt = 0; nt < 4; ++nt) acc[mt][nt] = zero;

    int nk = K >> 5;
    int wr = wid >> 1, wc = wid & 1;
    int rA = wr * 64 + (lane & 15);
    int rB = wc * 64 + (lane & 15);
    int kch = (lane >> 4) << 4;   // byte offset of 16B k-chunk

    for (int kt = 0; kt < nk; ++kt) {
        int kc = kt << 5;
#pragma unroll
        for (int i = 0; i < 2; ++i) {
            int off = wid * 2048 + i * 1024 + lane * 16;  // linear byte in 8KB tile
            int r = off >> 6, cb = off & 63;
            __builtin_amdgcn_global_load_lds((const u32*)((const char*)A + ((size_t)(row0 + r) * K + kc) * 2 + cb),
                                             (u32*)(ldsc + wid * 2048 + i * 1024), 16, 0, 0);
            __builtin_amdgcn_global_load_lds((const u32*)((const char*)BT + ((size_t)(col0 + r) * K + kc) * 2 + cb),
                                             (u32*)(ldsc + 8192 + wid * 2048 + i * 1024), 16, 0, 0);
        }
        __syncthreads();
        bf16x8 af[4], bfr[4];
#pragma unroll
        for (int mt = 0; mt < 4; ++mt)
            af[mt] = *(const bf16x8*)(ldsc + (rA + mt * 16) * 64 + kch);
#pragma unroll
        for (int nt = 0; nt < 4; ++nt)
            bfr[nt] = *(const bf16x8*)(ldsc + 8192 + (rB + nt * 16) * 64 + kch);
#pragma unroll
        for (int mt = 0; mt < 4; ++mt)
#pragma unroll
            for (int nt = 0; nt < 4; ++nt)
                acc[mt][nt] = __builtin_amdgcn_mfma_f32_16x16x32_bf16(af[mt], bfr[nt], acc[mt][nt], 0, 0, 0);
        __syncthreads();
    }

    int colb = col0 + wc * 64 + (lane & 15);
    int rowb = row0 + wr * 64 + ((lane >> 4) << 2);
#pragma unroll
    for (int mt = 0; mt < 4; ++mt)
#pragma unroll
        for (int nt = 0; nt < 4; ++nt)
#pragma unroll
            for (int r = 0; r < 4; ++r) {
                int row = rowb + mt * 16 + r;
                int c = colb + nt * 16;
                float v = acc[mt][nt][r];
                if (OUTMODE == 0) ((float*)Out)[(size_t)row * Mtot + c] = v;
                else if (OUTMODE == 1) ((u16*)Out)[(size_t)row * Mtot + c] = f2bf(v);
                else ((float*)Out)[(size_t)row * Mtot + c] = v + bias[c];
            }
}

// ---------------- LayerNorm kernels ----------------

__device__ __forceinline__ float wave_sum64(float v) {
#pragma unroll
    for (int off = 32; off > 0; off >>= 1) v += __shfl_xor(v, off, 64);
    return v;
}

__global__ __launch_bounds__(256) void ln_relu_k(const float* __restrict__ tmp,
                                                 const float* __restrict__ bias,
                                                 const float* __restrict__ g,
                                                 const float* __restrict__ be,
                                                 u16* __restrict__ h) {
    int wid = threadIdx.x >> 6, lane = threadIdx.x & 63;
    size_t row = (size_t)blockIdx.x * 4 + wid;
    const float* p = tmp + row * 128;
    int c = lane * 2;
    float v0 = p[c] + bias[c], v1 = p[c + 1] + bias[c + 1];
    float mu = wave_sum64(v0 + v1) * (1.f / 128.f);
    float d0 = v0 - mu, d1 = v1 - mu;
    float var = wave_sum64(d0 * d0 + d1 * d1) * (1.f / 128.f);
    float rs = rsqrtf(var + 1e-5f);
    float o0 = d0 * rs * g[c] + be[c];
    float o1 = d1 * rs * g[c + 1] + be[c + 1];
    o0 = o0 < 0.f ? 0.f : o0;
    o1 = o1 < 0.f ? 0.f : o1;
    ushort2 u; u.x = f2bf(o0); u.y = f2bf(o1);
    *(ushort2*)(h + row * 128 + c) = u;
}

__global__ __launch_bounds__(256) void ln2_k(const float* __restrict__ tmp,
                                             u16* __restrict__ h,
                                             const float* __restrict__ mg,
                                             const float* __restrict__ mb,
                                             const float* __restrict__ eg,
                                             const float* __restrict__ eb) {
    int wid = threadIdx.x >> 6, lane = threadIdx.x & 63;
    size_t row = (size_t)blockIdx.x * 4 + wid;
    const float* p = tmp + row * 128;
    int c = lane * 2;
    float v0 = p[c], v1 = p[c + 1];
    float mu = wave_sum64(v0 + v1) * (1.f / 128.f);
    float d0 = v0 - mu, d1 = v1 - mu;
    float var = wave_sum64(d0 * d0 + d1 * d1) * (1.f / 128.f);
    float rs = rsqrtf(var + 1e-5f);
    float o0 = d0 * rs * mg[c] + mb[c];
    float o1 = d1 * rs * mg[c + 1] + mb[c + 1];
    ushort2 xb = *(ushort2*)(h + row * 128 + c);
    float z0 = o0 + bf2f(xb.x), z1 = o1 + bf2f(xb.y);
    float mu2 = wave_sum64(z0 + z1) * (1.f / 128.f);
    float e0 = z0 - mu2, e1 = z1 - mu2;
    float var2 = wave_sum64(e0 * e0 + e1 * e1) * (1.f / 128.f);
    float rs2 = rsqrtf(var2 + 1e-5f);
    ushort2 u;
    u.x = f2bf(e0 * rs2 * eg[c] + eb[c]);
    u.y = f2bf(e1 * rs2 * eg[c + 1] + eb[c + 1]);
    *(ushort2*)(h + row * 128 + c) = u;
}

// ---------------- fused attention ----------------

__global__ __launch_bounds__(512) void attn_k(const u16* __restrict__ qkv,
                                              const float* __restrict__ mat,
                                              u16* __restrict__ ctx) {
    __shared__ __align__(16) u16 Klds[256 * 72];
    __shared__ __align__(16) u16 Vt[64 * 264];
    __shared__ __align__(16) u16 P[8 * 16 * 264];
    int t = threadIdx.x, lane = t & 63, w = t >> 6;
    int qc = blockIdx.x, hh = blockIdx.y, b = blockIdx.z;
    int nbase = b * LL;

    if (t < 256) {
        const u16* src = qkv + (size_t)(nbase + t) * 768 + 256 + hh * 64;
#pragma unroll
        for (int i = 0; i < 8; ++i)
            *(uint4*)(Klds + t * 72 + i * 8) = *(const uint4*)(src + i * 8);
    } else {
        int n = t - 256;
        const u16* src = qkv + (size_t)(nbase + n) * 768 + 512 + hh * 64;
#pragma unroll
        for (int i = 0; i < 8; ++i) {
            uint4 val = *(const uint4*)(src + i * 8);
            const u16* pv = (const u16*)&val;
#pragma unroll
            for (int j = 0; j < 8; ++j) Vt[(i * 8 + j) * 264 + n] = pv[j];
        }
    }
    __syncthreads();

    int qrow_l = qc * 128 + w * 16;
    const u16* qsrc = qkv + (size_t)(nbase + qrow_l + (lane & 15)) * 768 + hh * 64 + ((lane >> 4) << 3);
    bf16x8 aq0 = *(const bf16x8*)(qsrc);
    bf16x8 aq1 = *(const bf16x8*)(qsrc + 32);

    f32x4 zero = {0.f, 0.f, 0.f, 0.f};
    f32x4 sc[16];
#pragma unroll
    for (int nt = 0; nt < 16; ++nt) {
        f32x4 a = zero;
        int roff = (nt * 16 + (lane & 15)) * 72 + ((lane >> 4) << 3);
        bf16x8 k0 = *(const bf16x8*)(Klds + roff);
        bf16x8 k1 = *(const bf16x8*)(Klds + roff + 32);
        a = __builtin_amdgcn_mfma_f32_16x16x32_bf16(aq0, k0, a, 0, 0, 0);
        a = __builtin_amdgcn_mfma_f32_16x16x32_bf16(aq1, k1, a, 0, 0, 0);
        sc[nt] = a;
    }

    int rloc = (lane >> 4) << 2;
    const float* mrow = mat + ((size_t)b * LL + qrow_l + rloc) * LL;
#pragma unroll
    for (int nt = 0; nt < 16; ++nt) {
        int col = nt * 16 + (lane & 15);
#pragma unroll
        for (int r = 0; r < 4; ++r)
            sc[nt][r] *= 0.125f * mrow[r * LL + col];
    }

    float mx[4] = {-1e30f, -1e30f, -1e30f, -1e30f};
#pragma unroll
    for (int nt = 0; nt < 16; ++nt)
#pragma unroll
        for (int r = 0; r < 4; ++r) mx[r] = fmaxf(mx[r], sc[nt][r]);
#pragma unroll
    for (int off = 1; off < 16; off <<= 1)
#pragma unroll
        for (int r = 0; r < 4; ++r) mx[r] = fmaxf(mx[r], __shfl_xor(mx[r], off, 64));
    float sm[4] = {0.f, 0.f, 0.f, 0.f};
#pragma unroll
    for (int nt = 0; nt < 16; ++nt)
#pragma unroll
        for (int r = 0; r < 4; ++r) {
            float e = __expf(sc[nt][r] - mx[r]);
            sc[nt][r] = e;
            sm[r] += e;
        }
#pragma unroll
    for (int off = 1; off < 16; off <<= 1)
#pragma unroll
        for (int r = 0; r < 4; ++r) sm[r] += __shfl_xor(sm[r], off, 64);
    float inv[4];
#pragma unroll
    for (int r = 0; r < 4; ++r) inv[r] = 1.f / sm[r];

    u16* Pw = P + w * (16 * 264);
#pragma unroll
    for (int nt = 0; nt < 16; ++nt)
#pragma unroll
        for (int r = 0; r < 4; ++r)
            Pw[(rloc + r) * 264 + nt * 16 + (lane & 15)] = f2bf(sc[nt][r] * inv[r]);

    f32x4 oa[4];
#pragma unroll
    for (int dt = 0; dt < 4; ++dt) oa[dt] = zero;
#pragma unroll
    for (int kt = 0; kt < 8; ++kt) {
        bf16x8 pa = *(const bf16x8*)(Pw + (lane & 15) * 264 + kt * 32 + ((lane >> 4) << 3));
#pragma unroll
        for (int dt = 0; dt < 4; ++dt) {
            bf16x8 bv = *(const bf16x8*)(Vt + (dt * 16 + (lane & 15)) * 264 + kt * 32 + ((lane >> 4) << 3));
            oa[dt] = __builtin_amdgcn_mfma_f32_16x16x32_bf16(pa, bv, oa[dt], 0, 0, 0);
        }
    }
#pragma unroll
    for (int dt = 0; dt < 4; ++dt)
#pragma unroll
        for (int r = 0; r < 4; ++r)
            ctx[(size_t)(nbase + qrow_l + rloc + r) * 256 + hh * 64 + dt * 16 + (lane & 15)] = f2bf(oa[dt][r]);
}

// ---------------- naive comparators (diagnostic; sliced) ----------------

__global__ __launch_bounds__(256) void c0_edges(const float* __restrict__ x, const int* __restrict__ srcI,
                                                const int* __restrict__ dstI, const float* __restrict__ ew,
                                                float* __restrict__ scr) {
    int id = blockIdx.x * 256 + threadIdx.x;
    if (id >= 4096 * 10) return;
    int e = id / 10, q = id % 10;
    int s = srcI[e], d = dstI[e];
    float w = ew[e];
    for (int j = 0; j < 4; ++j)
        atomicAdd(&scr[d * 40 + q * 4 + j], w * x[(size_t)s * 40 + q * 4 + j]);
}

__global__ __launch_bounds__(256) void c0_cmp(const u16* __restrict__ Acat, const float* __restrict__ scr,
                                              const float* __restrict__ x, float* __restrict__ diag) {
    int i = blockIdx.x * 256 + threadIdx.x;
    if (i >= 256 * 128) return;
    int n = i >> 7, c = i & 127;
    float ex = 0.f;
    if (c < 40) ex = scr[n * 40 + c];
    else if (c >= 64 && c < 104) ex = x[(size_t)n * 40 + (c - 64)];
    dmax(&diag[0], fabsf(bf2f(Acat[(size_t)n * 128 + c]) - ex));
}

__global__ __launch_bounds__(256) void c1_cmp(const u16* __restrict__ Acat, const float* __restrict__ rel,
                                              const float* __restrict__ root, const float* __restrict__ tmp,
                                              float* __restrict__ diag) {
    int i = blockIdx.x * 256 + threadIdx.x;
    if (i >= 512 * 128) return;
    int n = i >> 7, d = i & 127;
    float s = 0.f;
    for (int k = 0; k < 40; ++k) s += bf2f(Acat[(size_t)n * 128 + k]) * bf2f(f2bf(rel[k * 128 + d]));
    for (int k = 0; k < 40; ++k) s += bf2f(Acat[(size_t)n * 128 + 64 + k]) * bf2f(f2bf(root[k * 128 + d]));
    dmax(&diag[1], fabsf(s - tmp[(size_t)n * 128 + d]));
}

__global__ __launch_bounds__(256) void c2_cmp(const float* __restrict__ tmp, const float* __restrict__ bias,
                                              const float* __restrict__ g, const float* __restrict__ be,
                                              const u16* __restrict__ h, float* __restrict__ diag) {
    int n = blockIdx.x * 256 + threadIdx.x;
    if (n >= 2048) return;
    const float* p = tmp + (size_t)n * 128;
    float mu = 0.f;
    for (int k = 0; k < 128; ++k) mu += p[k] + bias[k];
    mu *= (1.f / 128.f);
    float var = 0.f;
    for (int k = 0; k < 128; ++k) { float d = p[k] + bias[k] - mu; var += d * d; }
    float rs = rsqrtf(var * (1.f / 128.f) + 1e-5f);
    float md = 0.f;
    for (int k = 0; k < 128; ++k) {
        float o = (p[k] + bias[k] - mu) * rs * g[k] + be[k];
        o = o < 0.f ? 0.f : o;
        md = fmaxf(md, fabsf(o - bf2f(h[(size_t)n * 128 + k])));
    }
    dmax(&diag[2], md);
}

__global__ __launch_bounds__(256) void c3_cmp(const u16* __restrict__ h, const float* __restrict__ wq,
                                              const float* __restrict__ wk, const float* __restrict__ wv,
                                              const u16* __restrict__ qkv, float* __restrict__ diag) {
    int i = blockIdx.x * 256 + threadIdx.x;
    if (i >= 512 * 768) return;
    int n = i / 768, m = i % 768;
    const float* w = (m < 256) ? wq : (m < 512) ? wk : wv;
    int mm = m & 255;
    float s = 0.f;
    for (int k = 0; k < 128; ++k) s += bf2f(h[(size_t)n * 128 + k]) * bf2f(f2bf(w[k * 256 + mm]));
    dmax(&diag[3], fabsf(s - bf2f(qkv[(size_t)n * 768 + m])));
}

__global__ __launch_bounds__(256) void c4_cmp(const u16* __restrict__ qkv, const float* __restrict__ adj,
                                              const float* __restrict__ dis, const u16* __restrict__ ctx,
                                              float* __restrict__ diag) {
    int gw = (blockIdx.x * 256 + threadIdx.x) >> 6;   // 1024 waves: b=0, (hh,q)
    int lane = threadIdx.x & 63;
    int hh = gw >> 8, q = gw & 255;
    float qd = bf2f(qkv[(size_t)q * 768 + hh * 64 + lane]);
    float m = -1e30f, sum = 0.f, acc = 0.f;
    for (int k = 0; k < 256; ++k) {
        float s = qd * bf2f(qkv[(size_t)k * 768 + 256 + hh * 64 + lane]);
#pragma unroll
        for (int off = 1; off < 64; off <<= 1) s += __shfl_xor(s, off, 64);
        float mv = matfn(adj[(size_t)q * 256 + k], dis[(size_t)q * 256 + k]);
        s = s * 0.125f * mv;
        float mn = fmaxf(m, s);
        float rescale = __expf(m - mn);
        float pe = __expf(s - mn);
        sum = sum * rescale + pe;
        acc = acc * rescale + pe * bf2f(qkv[(size_t)k * 768 + 512 + hh * 64 + lane]);
        m = mn;
    }
    float o = acc / sum;
    float d = fabsf(o - bf2f(ctx[(size_t)q * 256 + hh * 64 + lane]));
#pragma unroll
    for (int off = 1; off < 64; off <<= 1) d = fmaxf(d, __shfl_xor(d, off, 64));
    if (lane == 0) dmax(&diag[4], d);
}

__global__ __launch_bounds__(256) void c5_cmp(const u16* __restrict__ ctx, const float* __restrict__ fc0,
                                              const float* __restrict__ tmp, float* __restrict__ diag) {
    int i = blockIdx.x * 256 + threadIdx.x;
    if (i >= 512 * 128) return;
    int n = i >> 7, d = i & 127;
    float s = 0.f;
    for (int k = 0; k < 256; ++k) s += bf2f(ctx[(size_t)n * 256 + k]) * bf2f(f2bf(fc0[k * 128 + d]));
    dmax(&diag[5], fabsf(s - tmp[(size_t)n * 128 + d]));
}

__global__ __launch_bounds__(256) void copyh_k(const u16* __restrict__ h, u16* __restrict__ hsave) {
    int i = blockIdx.x * 256 + threadIdx.x;
    if (i < 2048 * 128) hsave[i] = h[i];
}

__global__ __launch_bounds__(256) void c6_cmp(const float* __restrict__ tmp, const u16* __restrict__ hsave,
                                              const float* __restrict__ mg, const float* __restrict__ mb,
                                              const float* __restrict__ eg, const float* __restrict__ eb,
                                              const u16* __restrict__ h, float* __restrict__ diag) {
    int n = blockIdx.x * 256 + threadIdx.x;
    if (n >= 2048) return;
    const float* p = tmp + (size_t)n * 128;
    float mu = 0.f;
    for (int k = 0; k < 128; ++k) mu += p[k];
    mu *= (1.f / 128.f);
    float var = 0.f;
    for (int k = 0; k < 128; ++k) { float d = p[k] - mu; var += d * d; }
    float rs = rsqrtf(var * (1.f / 128.f) + 1e-5f);
    float mu2 = 0.f;
    for (int k = 0; k < 128; ++k) {
        float o = (p[k] - mu) * rs * mg[k] + mb[k];
        mu2 += o + bf2f(hsave[(size_t)n * 128 + k]);
    }
    mu2 *= (1.f / 128.f);
    float var2 = 0.f;
    for (int k = 0; k < 128; ++k) {
        float o = (p[k] - mu) * rs * mg[k] + mb[k];
        float z = o + bf2f(hsave[(size_t)n * 128 + k]) - mu2;
        var2 += z * z;
    }
    float rs2 = rsqrtf(var2 * (1.f / 128.f) + 1e-5f);
    float md = 0.f;
    for (int k = 0; k < 128; ++k) {
        float o = (p[k] - mu) * rs * mg[k] + mb[k];
        float z = o + bf2f(hsave[(size_t)n * 128 + k]) - mu2;
        float out = z * rs2 * eg[k] + eb[k];
        md = fmaxf(md, fabsf(out - bf2f(h[(size_t)n * 128 + k])));
    }
    dmax(&diag[6], md);
}

__global__ __launch_bounds__(256) void c7_edges(const u16* __restrict__ h, const int* __restrict__ srcI,
                                                const int* __restrict__ dstI, const float* __restrict__ ew,
                                                float* __restrict__ scr) {
    int id = blockIdx.x * 256 + threadIdx.x;
    if (id >= 4096 * 32) return;
    int e = id >> 5, kq = id & 31;
    int s = srcI[e], d = dstI[e];
    float w = ew[e];
    for (int j = 0; j < 4; ++j)
        atomicAdd(&scr[d * 128 + kq * 4 + j], w * bf2f(h[(size_t)s * 128 + kq * 4 + j]));
}

__global__ __launch_bounds__(256) void c7_cmp(const u16* __restrict__ Acat, const float* __restrict__ scr,
                                              const u16* __restrict__ h, float* __restrict__ diag) {
    int i = blockIdx.x * 256 + threadIdx.x;
    if (i >= 256 * 256) return;
    int n = i >> 8, c = i & 255;
    float got = bf2f(Acat[(size_t)n * 256 + c]);
    float ex = (c < 128) ? scr[n * 128 + c] : bf2f(h[(size_t)n * 128 + (c - 128)]);
    dmax(&diag[7], fabsf(got - ex));
}

__global__ __launch_bounds__(256) void c8_cmp(const u16* __restrict__ h, const float* __restrict__ pw,
                                              const float* __restrict__ pb, const float* __restrict__ out,
                                              float* __restrict__ diag) {
    int i = blockIdx.x * 256 + threadIdx.x;
    if (i >= 512 * 128) return;
    int n = i >> 7, d = i & 127;
    float s = pb[d];
    for (int k = 0; k < 128; ++k) s += bf2f(h[(size_t)n * 128 + k]) * bf2f(f2bf(pw[k * 128 + d]));
    dmax(&diag[8], fabsf(s - out[(size_t)n * 128 + d]));
}

__global__ __launch_bounds__(256) void c9_cmp(const u16* __restrict__ Acat, const float* __restrict__ rel,
                                              const float* __restrict__ root, const float* __restrict__ tmp,
                                              float* __restrict__ diag) {
    int i = blockIdx.x * 256 + threadIdx.x;
    if (i >= 256 * 128) return;
    int n = i >> 7, d = i & 127;
    float s = 0.f;
    for (int k = 0; k < 128; ++k) s += bf2f(Acat[(size_t)n * 256 + k]) * bf2f(f2bf(rel[k * 128 + d]));
    for (int k = 0; k < 128; ++k) s += bf2f(Acat[(size_t)n * 256 + 128 + k]) * bf2f(f2bf(root[k * 128 + d]));
    dmax(&diag[9], fabsf(s - tmp[(size_t)n * 128 + d]));
}

// Encode failures as a LARGE FLOAT added to out[1] (visible under f32 output read).
__global__ void diag_enc(const float* __restrict__ diag, float* __restrict__ out) {
    if (threadIdx.x || blockIdx.x) return;
    const float tol[10] = {0.5f, 0.3f, 0.3f, 0.3f, 0.3f, 0.3f, 0.3f, 0.5f, 0.3f, 0.5f};
    const float scl[10] = {1e3f, 4e3f, 1.6e4f, 6.4e4f, 2.56e5f,
                           1.024e6f, 4.096e6f, 1.6384e7f, 6.5536e7f, 2.62144e8f};
    float add = 0.f;
    for (int i = 0; i < 10; ++i) if (diag[i] > tol[i]) add += scl[i];
    if (add > 0.f) out[1] += add;
}

// ---------------- host launch ----------------

extern "C" void kernel_launch(void* const* d_in, const int* in_sizes, int n_in,
                              void* d_out, int out_size, void* d_ws, size_t ws_size,
                              hipStream_t stream) {
    (void)out_size; (void)ws_size; (void)n_in;
    const float* x        = (const float*)d_in[0];
    const int*   ei       = (const int*)d_in[1];
    const float* ea       = (const float*)d_in[2];
    const float* adj      = (const float*)d_in[3];
    const float* dis      = (const float*)d_in[4];
    // params start at 6 normally (mask at 5); if mask was dropped, at 5.
    int pb = (in_sizes[5] == 5120) ? 5 : 6;
    const float* g0_rel_w = (const float*)d_in[pb + 0];
    const float* g0_rel_b = (const float*)d_in[pb + 1];
    const float* g0_root_w= (const float*)d_in[pb + 2];
    const float* g_rel_w  = (const float*)d_in[pb + 3];
    const float* g_rel_b  = (const float*)d_in[pb + 4];
    const float* g_root_w = (const float*)d_in[pb + 5];
    const float* nm_g     = (const float*)d_in[pb + 6];
    const float* nm_b     = (const float*)d_in[pb + 7];
    const float* wq       = (const float*)d_in[pb + 8];
    const float* wk       = (const float*)d_in[pb + 9];
    const float* wv       = (const float*)d_in[pb + 10];
    const float* fc       = (const float*)d_in[pb + 11];
    const float* mha_g    = (const float*)d_in[pb + 12];
    const float* mha_b    = (const float*)d_in[pb + 13];
    const float* enc_g    = (const float*)d_in[pb + 14];
    const float* enc_b    = (const float*)d_in[pb + 15];
    const float* proj_w   = (const float*)d_in[pb + 16];
    const float* proj_b   = (const float*)d_in[pb + 17];
    const int* srcI = ei;
    const int* dstI = ei + EDGES;

    char* w = (char*)d_ws;
    float* mat    = (float*)w; w += (size_t)33554432;
    u16*   Acat   = (u16*)w;   w += (size_t)16777216;   // ctx aliases this
    u16*   h      = (u16*)w;   w += (size_t)8388608;
    u16*   qkv    = (u16*)w;   w += (size_t)50331648;   // tmp aliases tail
    u16*   hsave  = (u16*)w;   w += (size_t)524288;
    float* scr    = (float*)w; w += (size_t)131072;
    float* diag   = (float*)w; w += (size_t)256;
    u16* wconvT0  = (u16*)w;   w += (size_t)32768;
    u16* wconvT   = (u16*)w;   w += (size_t)196608;
    u16* wqkvT    = (u16*)w;   w += (size_t)786432;
    u16* fcT      = (u16*)w;   w += (size_t)262144;
    u16* projT    = (u16*)w;   w += (size_t)32768;
    u16*   ctx = Acat;
    float* tmp = (float*)((char*)qkv + 33554432);

    zero_f32<<<1, 256, 0, stream>>>(diag, 64);
    build_matrix_k<<<32768, 256, 0, stream>>>(adj, dis, mat, NB * LL * LL);
    build_wconvT0_k<<<64, 256, 0, stream>>>(g0_rel_w, g0_root_w, wconvT0);
    for (int i = 0; i < 3; ++i)
        build_wconvT_k<<<128, 256, 0, stream>>>(g_rel_w + i * 16384, g_root_w + i * 16384,
                                                wconvT + i * 32768);
    for (int i = 0; i < 4; ++i)
        build_wqkvT_k<<<384, 256, 0, stream>>>(wq + i * 32768, wk + i * 32768, wv + i * 32768,
                                               wqkvT + i * 98304);
    for (int i = 0; i < 4; ++i)
        transpose_cast_k<<<128, 256, 0, stream>>>(fc + i * 32768, fcT + i * 32768, 256, 128);
    transpose_cast_k<<<64, 256, 0, stream>>>(proj_w, projT, 128, 128);

    for (int L = 0; L < 4; ++L) {
        if (L == 0) {
            agg0_kernel<<<NB, 256, 0, stream>>>(x, srcI, dstI, ea, Acat);
            zero_f32<<<128, 256, 0, stream>>>(scr, 32768);
            c0_edges<<<160, 256, 0, stream>>>(x, srcI, dstI, ea, scr);
            c0_cmp<<<128, 256, 0, stream>>>(Acat, scr, x, diag);
        } else {
            agg_kernel<<<NB, 256, 0, stream>>>(h, srcI, dstI, ea, Acat);
            if (L == 1) {
                zero_f32<<<128, 256, 0, stream>>>(scr, 32768);
                c7_edges<<<512, 256, 0, stream>>>(h, srcI, dstI, ea, scr);
                c7_cmp<<<256, 256, 0, stream>>>(Acat, scr, h, diag);
            }
        }
        int K = (L == 0) ? 128 : 256;
        const u16* wct = (L == 0) ? wconvT0 : (wconvT + (L - 1) * 32768);
        gemm_bt<0><<<dim3(256, 1), 256, 0, stream>>>(Acat, wct, (void*)tmp, nullptr, K, 128);
        if (L == 0) c1_cmp<<<256, 256, 0, stream>>>(Acat, g0_rel_w, g0_root_w, tmp, diag);
        if (L == 1) c9_cmp<<<128, 256, 0, stream>>>(Acat, g_rel_w, g_root_w, tmp, diag);
        const float* rb = (L == 0) ? g0_rel_b : (g_rel_b + (L - 1) * 128);
        ln_relu_k<<<8192, 256, 0, stream>>>(tmp, rb, nm_g + L * 128, nm_b + L * 128, h);
        if (L == 0) c2_cmp<<<8, 256, 0, stream>>>(tmp, rb, nm_g, nm_b, h, diag);
        gemm_bt<1><<<dim3(256, 6), 256, 0, stream>>>(h, wqkvT + L * 98304, (void*)qkv, nullptr, 128, 768);
        if (L == 0) c3_cmp<<<1536, 256, 0, stream>>>(h, wq, wk, wv, qkv, diag);
        attn_k<<<dim3(2, 4, NB), 512, 0, stream>>>(qkv, mat, ctx);
        if (L == 0) c4_cmp<<<256, 256, 0, stream>>>(qkv, adj, dis, ctx, diag);
        gemm_bt<0><<<dim3(256, 1), 256, 0, stream>>>(ctx, fcT + L * 32768, (void*)tmp, nullptr, 256, 128);
        if (L == 0) c5_cmp<<<256, 256, 0, stream>>>(ctx, fc, tmp, diag);
        if (L == 0) copyh_k<<<1024, 256, 0, stream>>>(h, hsave);
        ln2_k<<<8192, 256, 0, stream>>>(tmp, h, mha_g + L * 128, mha_b + L * 128,
                                        enc_g + L * 128, enc_b + L * 128);
        if (L == 0) c6_cmp<<<8, 256, 0, stream>>>(tmp, hsave, mha_g, mha_b, enc_g, enc_b, h, diag);
    }
    gemm_bt<2><<<dim3(256, 1), 256, 0, stream>>>(h, projT, d_out, proj_b, 128, 128);
    c8_cmp<<<256, 256, 0, stream>>>(h, proj_w, proj_b, (const float*)d_out, diag);
    diag_enc<<<1, 64, 0, stream>>>(diag, (float*)d_out);
}

// Round 4
// 595.058 us; speedup vs baseline: 5.3503x; 5.3503x over previous
//
#include <hip/hip_runtime.h>
#include <stdint.h>

typedef unsigned short u16;
typedef unsigned int u32;
typedef __attribute__((ext_vector_type(4))) float f32x4;
typedef __attribute__((ext_vector_type(8))) short bf16x8;

#define NB 128      // graphs
#define LL 256      // nodes per graph
#define DD 128      // hidden
#define EDGES 524288
#define EPG 4096    // edges per graph
#define NN (NB*LL)

__device__ __forceinline__ float bf2f(u16 u) {
    union { u32 i; float f; } v; v.i = ((u32)u) << 16; return v.f;
}
__device__ __forceinline__ u16 f2bf(float f) {
    union { float f; u32 i; } v; v.f = f;
    u32 i = v.i;
    u32 r = (i + 0x7fffu + ((i >> 16) & 1u)) >> 16;   // RNE
    return (u16)r;
}
__device__ __forceinline__ float matfn(float a, float dv) {
    if (a != 0.f) return (a == 1.2f) ? 1.1f : a;
    return (dv == 0.f) ? 0.f : exp2f((1.f - dv) * 0.5849625007211562f); // 1.5^(1-dis)
}

// ---------------- prep kernels ----------------

__global__ __launch_bounds__(256) void build_matrix_k(const float* __restrict__ adj,
                                                      const float* __restrict__ dis,
                                                      float* __restrict__ mat, int n) {
    int i = blockIdx.x * 256 + threadIdx.x;
    if (i >= n) return;
    mat[i] = matfn(adj[i], dis[i]);
}

__global__ __launch_bounds__(256) void zero_f32(float* __restrict__ p, int n) {
    int i = blockIdx.x * 256 + threadIdx.x;
    if (i < n) p[i] = 0.f;
}

// W[b][dst][src] += ew  (f32 global atomics; edges of graph b are e in [b*4096,(b+1)*4096))
__global__ __launch_bounds__(256) void scatter_w_k(const int* __restrict__ srcI,
                                                   const int* __restrict__ dstI,
                                                   const float* __restrict__ ew,
                                                   float* __restrict__ Wf) {
    int e = blockIdx.x * 256 + threadIdx.x;
    if (e >= EDGES) return;
    int b = e >> 12;
    atomicAdd(&Wf[(size_t)b * 65536 + (size_t)(dstI[e] & 255) * 256 + (srcI[e] & 255)], ew[e]);
}

__global__ __launch_bounds__(256) void cast_w_k(const float* __restrict__ Wf, u16* __restrict__ Wb) {
    int i = blockIdx.x * 256 + threadIdx.x;   // 2M float4 groups
    float4 v = ((const float4*)Wf)[i];
    ushort4 o;
    o.x = f2bf(v.x); o.y = f2bf(v.y); o.z = f2bf(v.z); o.w = f2bf(v.w);
    ((ushort4*)Wb)[i] = o;
}

__global__ __launch_bounds__(256) void build_wconvT0_k(const float* __restrict__ rel,
                                                       const float* __restrict__ root,
                                                       u16* __restrict__ dst) {
    int i = blockIdx.x * 256 + threadIdx.x;   // 128*128
    int m = i >> 7, k = i & 127;
    float v = 0.f;
    if (k < 40) v = rel[k * 128 + m];
    else if (k >= 64 && k < 104) v = root[(k - 64) * 128 + m];
    dst[m * 128 + k] = f2bf(v);
}

__global__ __launch_bounds__(256) void build_wconvT_k(const float* __restrict__ rel,
                                                      const float* __restrict__ root,
                                                      u16* __restrict__ dst) {
    int i = blockIdx.x * 256 + threadIdx.x;   // 128*256
    int m = i >> 8, k = i & 255;
    float v = (k < 128) ? rel[k * 128 + m] : root[(k - 128) * 128 + m];
    dst[m * 256 + k] = f2bf(v);
}

__global__ __launch_bounds__(256) void build_wqkvT_k(const float* __restrict__ wq,
                                                     const float* __restrict__ wk,
                                                     const float* __restrict__ wv,
                                                     u16* __restrict__ dst) {
    int i = blockIdx.x * 256 + threadIdx.x;   // 768*128
    int m = i >> 7, k = i & 127;
    const float* s = (m < 256) ? wq : (m < 512) ? wk : wv;
    int mm = m & 255;
    dst[m * 128 + k] = f2bf(s[k * 256 + mm]);
}

__global__ __launch_bounds__(256) void transpose_cast_k(const float* __restrict__ src,
                                                        u16* __restrict__ dst, int K, int M) {
    int i = blockIdx.x * 256 + threadIdx.x;
    if (i >= K * M) return;
    int m = i / K, k = i - m * K;
    dst[i] = f2bf(src[k * M + m]);   // dst [M][K]
}

// per-graph transpose: h [N,128] bf16 (or x [N,40] f32, zero-padded) -> hT [b][128][256]
template<bool IS0>
__global__ __launch_bounds__(256) void transpose_h_k(const u16* __restrict__ h,
                                                     const float* __restrict__ x,
                                                     u16* __restrict__ hT) {
    int gw = blockIdx.x * 4 + (threadIdx.x >> 6);
    int lane = threadIdx.x & 63;
    int b = gw >> 6, rem = gw & 63, db = rem >> 5, jb = rem & 31;
    int d = (db << 6) + lane;
    u16 vals[8];
#pragma unroll
    for (int jj = 0; jj < 8; ++jj) {
        int node = (b << 8) + (jb << 3) + jj;
        if (IS0) vals[jj] = (d < 40) ? f2bf(x[(size_t)node * 40 + d]) : (u16)0;
        else     vals[jj] = h[(size_t)node * 128 + d];
    }
    *(uint4*)(hT + (size_t)b * 32768 + (size_t)d * 256 + (jb << 3)) = *(uint4*)vals;
}

// ---------------- per-graph aggregation GEMM: Acat = [W@h | h]  (K=256) ----------------

template<bool IS0>
__global__ __launch_bounds__(256) void gemm_agg(const u16* __restrict__ Wb,
                                                const u16* __restrict__ BT0,
                                                const u16* __restrict__ h,
                                                const float* __restrict__ x,
                                                u16* __restrict__ Acat) {
    __shared__ __align__(16) u16 lds[8192];   // A 8KB | B 8KB  ([128][32] bf16 each)
    char* ldsc = (char*)lds;
    int t = threadIdx.x, lane = t & 63, wid = t >> 6;
    int b = blockIdx.x >> 1, rt = blockIdx.x & 1;
    int row0 = rt << 7, nbase = b << 8;
    const u16* A = Wb + (size_t)b * 65536 + (size_t)row0 * 256;
    const u16* BT = BT0 + (size_t)b * 32768;

    f32x4 zero = {0.f, 0.f, 0.f, 0.f};
    f32x4 acc[4][4];
#pragma unroll
    for (int mt = 0; mt < 4; ++mt)
#pragma unroll
        for (int nt = 0; nt < 4; ++nt) acc[mt][nt] = zero;

    int wr = wid >> 1, wc = wid & 1;
    int rA = wr * 64 + (lane & 15);
    int rB = wc * 64 + (lane & 15);
    int kch = (lane >> 4) << 4;

    for (int kt = 0; kt < 8; ++kt) {
        int kc = kt << 5;
#pragma unroll
        for (int i = 0; i < 2; ++i) {
            int off = wid * 2048 + i * 1024 + lane * 16;
            int r = off >> 6, cb = off & 63;
            __builtin_amdgcn_global_load_lds((const u32*)((const char*)A + ((size_t)r * 256 + kc) * 2 + cb),
                                             (u32*)(ldsc + wid * 2048 + i * 1024), 16, 0, 0);
            __builtin_amdgcn_global_load_lds((const u32*)((const char*)BT + ((size_t)r * 256 + kc) * 2 + cb),
                                             (u32*)(ldsc + 8192 + wid * 2048 + i * 1024), 16, 0, 0);
        }
        __syncthreads();
        bf16x8 af[4], bfr[4];
#pragma unroll
        for (int mt = 0; mt < 4; ++mt)
            af[mt] = *(const bf16x8*)(ldsc + (rA + mt * 16) * 64 + kch);
#pragma unroll
        for (int nt = 0; nt < 4; ++nt)
            bfr[nt] = *(const bf16x8*)(ldsc + 8192 + (rB + nt * 16) * 64 + kch);
#pragma unroll
        for (int mt = 0; mt < 4; ++mt)
#pragma unroll
            for (int nt = 0; nt < 4; ++nt)
                acc[mt][nt] = __builtin_amdgcn_mfma_f32_16x16x32_bf16(af[mt], bfr[nt], acc[mt][nt], 0, 0, 0);
        __syncthreads();
    }

    int colb = wc * 64 + (lane & 15);
    int rowb = wr * 64 + ((lane >> 4) << 2);
#pragma unroll
    for (int mt = 0; mt < 4; ++mt)
#pragma unroll
        for (int nt = 0; nt < 4; ++nt)
#pragma unroll
            for (int r = 0; r < 4; ++r) {
                int i = rowb + mt * 16 + r;
                int c = colb + nt * 16;
                float v = acc[mt][nt][r];
                if (IS0) Acat[(size_t)(nbase + row0 + i) * 128 + c] = f2bf(v);
                else     Acat[(size_t)(nbase + row0 + i) * 256 + c] = f2bf(v);
            }
    if (IS0) {
        for (int idx = t; idx < 128 * 40; idx += 256) {
            int i = idx / 40, c = idx - i * 40;
            int node = nbase + row0 + i;
            Acat[(size_t)node * 128 + 64 + c] = f2bf(x[(size_t)node * 40 + c]);
        }
    } else {
        for (int idx = t; idx < 2048; idx += 256) {
            int i = idx >> 4, q = idx & 15;
            int node = nbase + row0 + i;
            *(uint4*)(Acat + (size_t)node * 256 + 128 + (q << 3)) =
                *(const uint4*)(h + (size_t)node * 128 + (q << 3));
        }
    }
}

// ---------------- bf16 GEMM (m97 structure) ----------------
// OUTMODE: 0 = f32 store, 1 = bf16 store, 2 = f32 store + f32 bias (final output)

template<int OUTMODE>
__global__ __launch_bounds__(256) void gemm_bt(const u16* __restrict__ A,
                                               const u16* __restrict__ BT,
                                               void* __restrict__ Out,
                                               const float* __restrict__ bias,
                                               int K, int Mtot) {
    __shared__ __align__(16) u16 lds[8192];
    char* ldsc = (char*)lds;
    int t = threadIdx.x, lane = t & 63, wid = t >> 6;
    int row0 = blockIdx.x * 128, col0 = blockIdx.y * 128;

    f32x4 zero = {0.f, 0.f, 0.f, 0.f};
    f32x4 acc[4][4];
#pragma unroll
    for (int mt = 0; mt < 4; ++mt)
#pragma unroll
        for (int nt = 0; nt < 4; ++nt) acc[mt][nt] = zero;

    int nk = K >> 5;
    int wr = wid >> 1, wc = wid & 1;
    int rA = wr * 64 + (lane & 15);
    int rB = wc * 64 + (lane & 15);
    int kch = (lane >> 4) << 4;

    for (int kt = 0; kt < nk; ++kt) {
        int kc = kt << 5;
#pragma unroll
        for (int i = 0; i < 2; ++i) {
            int off = wid * 2048 + i * 1024 + lane * 16;
            int r = off >> 6, cb = off & 63;
            __builtin_amdgcn_global_load_lds((const u32*)((const char*)A + ((size_t)(row0 + r) * K + kc) * 2 + cb),
                                             (u32*)(ldsc + wid * 2048 + i * 1024), 16, 0, 0);
            __builtin_amdgcn_global_load_lds((const u32*)((const char*)BT + ((size_t)(col0 + r) * K + kc) * 2 + cb),
                                             (u32*)(ldsc + 8192 + wid * 2048 + i * 1024), 16, 0, 0);
        }
        __syncthreads();
        bf16x8 af[4], bfr[4];
#pragma unroll
        for (int mt = 0; mt < 4; ++mt)
            af[mt] = *(const bf16x8*)(ldsc + (rA + mt * 16) * 64 + kch);
#pragma unroll
        for (int nt = 0; nt < 4; ++nt)
            bfr[nt] = *(const bf16x8*)(ldsc + 8192 + (rB + nt * 16) * 64 + kch);
#pragma unroll
        for (int mt = 0; mt < 4; ++mt)
#pragma unroll
            for (int nt = 0; nt < 4; ++nt)
                acc[mt][nt] = __builtin_amdgcn_mfma_f32_16x16x32_bf16(af[mt], bfr[nt], acc[mt][nt], 0, 0, 0);
        __syncthreads();
    }

    int colb = col0 + wc * 64 + (lane & 15);
    int rowb = row0 + wr * 64 + ((lane >> 4) << 2);
#pragma unroll
    for (int mt = 0; mt < 4; ++mt)
#pragma unroll
        for (int nt = 0; nt < 4; ++nt)
#pragma unroll
            for (int r = 0; r < 4; ++r) {
                int row = rowb + mt * 16 + r;
                int c = colb + nt * 16;
                float v = acc[mt][nt][r];
                if (OUTMODE == 0) ((float*)Out)[(size_t)row * Mtot + c] = v;
                else if (OUTMODE == 1) ((u16*)Out)[(size_t)row * Mtot + c] = f2bf(v);
                else ((float*)Out)[(size_t)row * Mtot + c] = v + bias[c];
            }
}

// ---------------- LayerNorm kernels ----------------

__device__ __forceinline__ float wave_sum64(float v) {
#pragma unroll
    for (int off = 32; off > 0; off >>= 1) v += __shfl_xor(v, off, 64);
    return v;
}

__global__ __launch_bounds__(256) void ln_relu_k(const float* __restrict__ tmp,
                                                 const float* __restrict__ bias,
                                                 const float* __restrict__ g,
                                                 const float* __restrict__ be,
                                                 u16* __restrict__ h) {
    int wid = threadIdx.x >> 6, lane = threadIdx.x & 63;
    size_t row = (size_t)blockIdx.x * 4 + wid;
    const float* p = tmp + row * 128;
    int c = lane * 2;
    float v0 = p[c] + bias[c], v1 = p[c + 1] + bias[c + 1];
    float mu = wave_sum64(v0 + v1) * (1.f / 128.f);
    float d0 = v0 - mu, d1 = v1 - mu;
    float var = wave_sum64(d0 * d0 + d1 * d1) * (1.f / 128.f);
    float rs = rsqrtf(var + 1e-5f);
    float o0 = d0 * rs * g[c] + be[c];
    float o1 = d1 * rs * g[c + 1] + be[c + 1];
    o0 = o0 < 0.f ? 0.f : o0;
    o1 = o1 < 0.f ? 0.f : o1;
    ushort2 u; u.x = f2bf(o0); u.y = f2bf(o1);
    *(ushort2*)(h + row * 128 + c) = u;
}

__global__ __launch_bounds__(256) void ln2_k(const float* __restrict__ tmp,
                                             u16* __restrict__ h,
                                             const float* __restrict__ mg,
                                             const float* __restrict__ mb,
                                             const float* __restrict__ eg,
                                             const float* __restrict__ eb) {
    int wid = threadIdx.x >> 6, lane = threadIdx.x & 63;
    size_t row = (size_t)blockIdx.x * 4 + wid;
    const float* p = tmp + row * 128;
    int c = lane * 2;
    float v0 = p[c], v1 = p[c + 1];
    float mu = wave_sum64(v0 + v1) * (1.f / 128.f);
    float d0 = v0 - mu, d1 = v1 - mu;
    float var = wave_sum64(d0 * d0 + d1 * d1) * (1.f / 128.f);
    float rs = rsqrtf(var + 1e-5f);
    float o0 = d0 * rs * mg[c] + mb[c];
    float o1 = d1 * rs * mg[c + 1] + mb[c + 1];
    ushort2 xb = *(ushort2*)(h + row * 128 + c);
    float z0 = o0 + bf2f(xb.x), z1 = o1 + bf2f(xb.y);
    float mu2 = wave_sum64(z0 + z1) * (1.f / 128.f);
    float e0 = z0 - mu2, e1 = z1 - mu2;
    float var2 = wave_sum64(e0 * e0 + e1 * e1) * (1.f / 128.f);
    float rs2 = rsqrtf(var2 + 1e-5f);
    ushort2 u;
    u.x = f2bf(e0 * rs2 * eg[c] + eb[c]);
    u.y = f2bf(e1 * rs2 * eg[c + 1] + eb[c + 1]);
    *(ushort2*)(h + row * 128 + c) = u;
}

// ---------------- fused attention ----------------

__global__ __launch_bounds__(512) void attn_k(const u16* __restrict__ qkv,
                                              const float* __restrict__ mat,
                                              u16* __restrict__ ctx) {
    __shared__ __align__(16) u16 Klds[256 * 72];
    __shared__ __align__(16) u16 Vt[64 * 264];
    __shared__ __align__(16) u16 P[8 * 16 * 264];
    int t = threadIdx.x, lane = t & 63, w = t >> 6;
    int qc = blockIdx.x, hh = blockIdx.y, b = blockIdx.z;
    int nbase = b * LL;

    if (t < 256) {
        const u16* src = qkv + (size_t)(nbase + t) * 768 + 256 + hh * 64;
#pragma unroll
        for (int i = 0; i < 8; ++i)
            *(uint4*)(Klds + t * 72 + i * 8) = *(const uint4*)(src + i * 8);
    } else {
        int n = t - 256;
        const u16* src = qkv + (size_t)(nbase + n) * 768 + 512 + hh * 64;
#pragma unroll
        for (int i = 0; i < 8; ++i) {
            uint4 val = *(const uint4*)(src + i * 8);
            const u16* pv = (const u16*)&val;
#pragma unroll
            for (int j = 0; j < 8; ++j) Vt[(i * 8 + j) * 264 + n] = pv[j];
        }
    }
    __syncthreads();

    int qrow_l = qc * 128 + w * 16;
    const u16* qsrc = qkv + (size_t)(nbase + qrow_l + (lane & 15)) * 768 + hh * 64 + ((lane >> 4) << 3);
    bf16x8 aq0 = *(const bf16x8*)(qsrc);
    bf16x8 aq1 = *(const bf16x8*)(qsrc + 32);

    f32x4 zero = {0.f, 0.f, 0.f, 0.f};
    f32x4 sc[16];
#pragma unroll
    for (int nt = 0; nt < 16; ++nt) {
        f32x4 a = zero;
        int roff = (nt * 16 + (lane & 15)) * 72 + ((lane >> 4) << 3);
        bf16x8 k0 = *(const bf16x8*)(Klds + roff);
        bf16x8 k1 = *(const bf16x8*)(Klds + roff + 32);
        a = __builtin_amdgcn_mfma_f32_16x16x32_bf16(aq0, k0, a, 0, 0, 0);
        a = __builtin_amdgcn_mfma_f32_16x16x32_bf16(aq1, k1, a, 0, 0, 0);
        sc[nt] = a;
    }

    int rloc = (lane >> 4) << 2;
    const float* mrow = mat + ((size_t)b * LL + qrow_l + rloc) * LL;
#pragma unroll
    for (int nt = 0; nt < 16; ++nt) {
        int col = nt * 16 + (lane & 15);
#pragma unroll
        for (int r = 0; r < 4; ++r)
            sc[nt][r] *= 0.125f * mrow[r * LL + col];
    }

    float mx[4] = {-1e30f, -1e30f, -1e30f, -1e30f};
#pragma unroll
    for (int nt = 0; nt < 16; ++nt)
#pragma unroll
        for (int r = 0; r < 4; ++r) mx[r] = fmaxf(mx[r], sc[nt][r]);
#pragma unroll
    for (int off = 1; off < 16; off <<= 1)
#pragma unroll
        for (int r = 0; r < 4; ++r) mx[r] = fmaxf(mx[r], __shfl_xor(mx[r], off, 64));
    float sm[4] = {0.f, 0.f, 0.f, 0.f};
#pragma unroll
    for (int nt = 0; nt < 16; ++nt)
#pragma unroll
        for (int r = 0; r < 4; ++r) {
            float e = __expf(sc[nt][r] - mx[r]);
            sc[nt][r] = e;
            sm[r] += e;
        }
#pragma unroll
    for (int off = 1; off < 16; off <<= 1)
#pragma unroll
        for (int r = 0; r < 4; ++r) sm[r] += __shfl_xor(sm[r], off, 64);
    float inv[4];
#pragma unroll
    for (int r = 0; r < 4; ++r) inv[r] = 1.f / sm[r];

    u16* Pw = P + w * (16 * 264);
#pragma unroll
    for (int nt = 0; nt < 16; ++nt)
#pragma unroll
        for (int r = 0; r < 4; ++r)
            Pw[(rloc + r) * 264 + nt * 16 + (lane & 15)] = f2bf(sc[nt][r] * inv[r]);

    f32x4 oa[4];
#pragma unroll
    for (int dt = 0; dt < 4; ++dt) oa[dt] = zero;
#pragma unroll
    for (int kt = 0; kt < 8; ++kt) {
        bf16x8 pa = *(const bf16x8*)(Pw + (lane & 15) * 264 + kt * 32 + ((lane >> 4) << 3));
#pragma unroll
        for (int dt = 0; dt < 4; ++dt) {
            bf16x8 bv = *(const bf16x8*)(Vt + (dt * 16 + (lane & 15)) * 264 + kt * 32 + ((lane >> 4) << 3));
            oa[dt] = __builtin_amdgcn_mfma_f32_16x16x32_bf16(pa, bv, oa[dt], 0, 0, 0);
        }
    }
#pragma unroll
    for (int dt = 0; dt < 4; ++dt)
#pragma unroll
        for (int r = 0; r < 4; ++r)
            ctx[(size_t)(nbase + qrow_l + rloc + r) * 256 + hh * 64 + dt * 16 + (lane & 15)] = f2bf(oa[dt][r]);
}

// ---------------- host launch ----------------

extern "C" void kernel_launch(void* const* d_in, const int* in_sizes, int n_in,
                              void* d_out, int out_size, void* d_ws, size_t ws_size,
                              hipStream_t stream) {
    (void)out_size; (void)ws_size; (void)n_in;
    const float* x        = (const float*)d_in[0];
    const int*   ei       = (const int*)d_in[1];
    const float* ea       = (const float*)d_in[2];
    const float* adj      = (const float*)d_in[3];
    const float* dis      = (const float*)d_in[4];
    int pb = (in_sizes[5] == 5120) ? 5 : 6;
    const float* g0_rel_w = (const float*)d_in[pb + 0];
    const float* g0_rel_b = (const float*)d_in[pb + 1];
    const float* g0_root_w= (const float*)d_in[pb + 2];
    const float* g_rel_w  = (const float*)d_in[pb + 3];
    const float* g_rel_b  = (const float*)d_in[pb + 4];
    const float* g_root_w = (const float*)d_in[pb + 5];
    const float* nm_g     = (const float*)d_in[pb + 6];
    const float* nm_b     = (const float*)d_in[pb + 7];
    const float* wq       = (const float*)d_in[pb + 8];
    const float* wk       = (const float*)d_in[pb + 9];
    const float* wv       = (const float*)d_in[pb + 10];
    const float* fc       = (const float*)d_in[pb + 11];
    const float* mha_g    = (const float*)d_in[pb + 12];
    const float* mha_b    = (const float*)d_in[pb + 13];
    const float* enc_g    = (const float*)d_in[pb + 14];
    const float* enc_b    = (const float*)d_in[pb + 15];
    const float* proj_w   = (const float*)d_in[pb + 16];
    const float* proj_b   = (const float*)d_in[pb + 17];
    const int* srcI = ei;
    const int* dstI = ei + EDGES;

    char* w = (char*)d_ws;
    float* Wf     = (float*)w; w += (size_t)33554432;   // W f32 scatter, then reused as `mat`
    u16*   Acat   = (u16*)w;   w += (size_t)16777216;   // ctx aliases this
    u16*   h      = (u16*)w;   w += (size_t)8388608;
    u16*   qkv    = (u16*)w;   w += (size_t)50331648;   // tmp aliases tail
    u16*   Wb     = (u16*)w;   w += (size_t)16777216;   // W bf16 [128][256][256]
    u16*   hT     = (u16*)w;   w += (size_t)8388608;    // per-graph transposed h / xbT
    u16* wconvT0  = (u16*)w;   w += (size_t)32768;
    u16* wconvT   = (u16*)w;   w += (size_t)196608;
    u16* wqkvT    = (u16*)w;   w += (size_t)786432;
    u16* fcT      = (u16*)w;   w += (size_t)262144;
    u16* projT    = (u16*)w;   w += (size_t)32768;
    float* mat = Wf;
    u16*   ctx = Acat;
    float* tmp = (float*)((char*)qkv + 33554432);

    // --- prep: W (edge-only, once), then mat reuses Wf buffer ---
    zero_f32<<<32768, 256, 0, stream>>>(Wf, 8388608);
    scatter_w_k<<<2048, 256, 0, stream>>>(srcI, dstI, ea, Wf);
    cast_w_k<<<8192, 256, 0, stream>>>(Wf, Wb);
    build_matrix_k<<<32768, 256, 0, stream>>>(adj, dis, mat, NB * LL * LL);

    build_wconvT0_k<<<64, 256, 0, stream>>>(g0_rel_w, g0_root_w, wconvT0);
    for (int i = 0; i < 3; ++i)
        build_wconvT_k<<<128, 256, 0, stream>>>(g_rel_w + i * 16384, g_root_w + i * 16384,
                                                wconvT + i * 32768);
    for (int i = 0; i < 4; ++i)
        build_wqkvT_k<<<384, 256, 0, stream>>>(wq + i * 32768, wk + i * 32768, wv + i * 32768,
                                               wqkvT + i * 98304);
    for (int i = 0; i < 4; ++i)
        transpose_cast_k<<<128, 256, 0, stream>>>(fc + i * 32768, fcT + i * 32768, 256, 128);
    transpose_cast_k<<<64, 256, 0, stream>>>(proj_w, projT, 128, 128);

    for (int L = 0; L < 4; ++L) {
        if (L == 0) {
            transpose_h_k<true><<<2048, 256, 0, stream>>>(h, x, hT);
            gemm_agg<true><<<256, 256, 0, stream>>>(Wb, hT, h, x, Acat);
        } else {
            transpose_h_k<false><<<2048, 256, 0, stream>>>(h, x, hT);
            gemm_agg<false><<<256, 256, 0, stream>>>(Wb, hT, h, x, Acat);
        }
        int K = (L == 0) ? 128 : 256;
        const u16* wct = (L == 0) ? wconvT0 : (wconvT + (L - 1) * 32768);
        gemm_bt<0><<<dim3(256, 1), 256, 0, stream>>>(Acat, wct, (void*)tmp, nullptr, K, 128);
        const float* rb = (L == 0) ? g0_rel_b : (g_rel_b + (L - 1) * 128);
        ln_relu_k<<<8192, 256, 0, stream>>>(tmp, rb, nm_g + L * 128, nm_b + L * 128, h);
        gemm_bt<1><<<dim3(256, 6), 256, 0, stream>>>(h, wqkvT + L * 98304, (void*)qkv, nullptr, 128, 768);
        attn_k<<<dim3(2, 4, NB), 512, 0, stream>>>(qkv, mat, ctx);
        gemm_bt<0><<<dim3(256, 1), 256, 0, stream>>>(ctx, fcT + L * 32768, (void*)tmp, nullptr, 256, 128);
        ln2_k<<<8192, 256, 0, stream>>>(tmp, h, mha_g + L * 128, mha_b + L * 128,
                                        enc_g + L * 128, enc_b + L * 128);
    }
    gemm_bt<2><<<dim3(256, 1), 256, 0, stream>>>(h, projT, d_out, proj_b, 128, 128);
}